// Round 15
// baseline (304.082 us; speedup 1.0000x reference)
//
#include <hip/hip_runtime.h>
#include <hip/hip_fp16.h>

// Problem constants (match reference)
constexpr int NN  = 50000;
constexpr int EEg = 1600000;          // edges before self-loops
constexpr int IND = 16;
constexpr int FD  = 20;
constexpr int H1D = 4;
constexpr int ED  = 7;
constexpr int OUTD = 3;
constexpr int FP  = 32;               // padded half-row (20 -> 32 halfs = 64B, line-aligned)

__device__ __forceinline__ float lrelu(float x) { return x >= 0.0f ? x : 0.2f * x; }
__device__ __forceinline__ float elu(float x)   { return x > 0.0f ? x : expm1f(x); }
__device__ __forceinline__ unsigned pack2(float a, float b) {
    __half2 h = __floats2half2_rn(a, b);
    return *(unsigned*)&h;
}
__device__ __forceinline__ float2 up2(unsigned w) {
    __half2 h = *(__half2*)&w;
    return __half22float2(h);
}

// ---- per-dst degree histogram; atomic return value = edge rank within dst ----
__global__ void k_deg(const int* __restrict__ ei, int* __restrict__ deg,
                      int* __restrict__ rank) {
    int e = blockIdx.x * blockDim.x + threadIdx.x;
    if (e >= EEg) return;
    rank[e] = atomicAdd(&deg[ei[EEg + e]], 1);
}

// ---- tiny: ve1[d*4+h] = sum_f We1[d,h*F+f]*att_e1[h,f]; ve2[d] likewise ----
__global__ void k_ve(const float* __restrict__ We1, const float* __restrict__ ae1,
                     const float* __restrict__ We2, const float* __restrict__ ae2,
                     float* __restrict__ ve1, float* __restrict__ ve2) {
    int t = threadIdx.x;
    if (t < ED * H1D) {
        int d = t >> 2, h = t & 3;
        float s = 0.0f;
        for (int f = 0; f < FD; ++f) s += We1[d * (H1D * FD) + h * FD + f] * ae1[h * FD + f];
        ve1[t] = s;
    } else if (t < ED * H1D + ED) {
        int d = t - ED * H1D;
        float s = 0.0f;
        for (int f = 0; f < FD; ++f) s += We2[d * FD + f] * ae2[f];
        ve2[d] = s;
    }
}

// ---- two-level exclusive scan for row_off ----
__global__ void k_scanA(const int* __restrict__ deg, int* __restrict__ partial,
                        int* __restrict__ bsum) {
    __shared__ int sd[256];
    int t = threadIdx.x, i = blockIdx.x * 256 + t;
    int v = (i < NN) ? deg[i] : 0;
    sd[t] = v;
    __syncthreads();
    for (int off = 1; off < 256; off <<= 1) {
        int u = (t >= off) ? sd[t - off] : 0;
        __syncthreads();
        sd[t] += u;
        __syncthreads();
    }
    if (i < NN) partial[i] = sd[t] - v;
    if (t == 255) bsum[blockIdx.x] = sd[255];
}
__global__ void k_scanB(const int* __restrict__ bsum, int* __restrict__ boff, int nb) {
    __shared__ int sd[256];
    int t = threadIdx.x;
    int v = (t < nb) ? bsum[t] : 0;
    sd[t] = v;
    __syncthreads();
    for (int off = 1; off < 256; off <<= 1) {
        int u = (t >= off) ? sd[t - off] : 0;
        __syncthreads();
        sd[t] += u;
        __syncthreads();
    }
    if (t < nb) boff[t] = sd[t] - v;
}
__global__ void k_scanC(const int* __restrict__ partial, const int* __restrict__ boff,
                        int* __restrict__ row_off) {
    int i = blockIdx.x * 256 + threadIdx.x;
    if (i < NN) row_off[i] = partial[i] + boff[blockIdx.x];
    if (i == 0) row_off[NN] = EEg;
}

// ---- scatter: ONE aligned 16B record per edge; eattr staged through LDS ----
// record: {x=src, y=half2(ae1_0,ae1_1), z=half2(ae1_2,ae1_3), w=half2(ae2,0)}
__global__ __launch_bounds__(256) void k_scatter(
        const int* __restrict__ ei, const float* __restrict__ eattr,
        const float* __restrict__ ve1, const float* __restrict__ ve2,
        const int* __restrict__ row_off, const int* __restrict__ rank,
        uint4* __restrict__ csr) {
    __shared__ float sv1[ED * H1D], sv2[ED];
    __shared__ float se[256 * ED];
    if (threadIdx.x < ED * H1D) sv1[threadIdx.x] = ve1[threadIdx.x];
    if (threadIdx.x < ED) sv2[threadIdx.x] = ve2[threadIdx.x];
    size_t gbase = (size_t)blockIdx.x * 256 * ED;
    for (int i = threadIdx.x; i < 256 * ED; i += 256) {
        size_t g = gbase + i;
        if (g < (size_t)EEg * ED) se[i] = eattr[g];
    }
    __syncthreads();
    int e = blockIdx.x * 256 + threadIdx.x;
    if (e >= EEg) return;
    int src = ei[e], dst = ei[EEg + e];
    const float* a = &se[threadIdx.x * ED];
    float v0 = 0.f, v1 = 0.f, v2 = 0.f, v3 = 0.f, w2 = 0.f;
#pragma unroll
    for (int d = 0; d < ED; ++d) {
        float ad = a[d];
        v0 += ad * sv1[d * H1D + 0];
        v1 += ad * sv1[d * H1D + 1];
        v2 += ad * sv1[d * H1D + 2];
        v3 += ad * sv1[d * H1D + 3];
        w2 += ad * sv2[d];
    }
    int slot = row_off[dst] + rank[e];
    uint4 rec;
    rec.x = (unsigned)src;
    rec.y = pack2(v0, v1);
    rec.z = pack2(v2, v3);
    rec.w = pack2(w2, 0.0f);
    csr[slot] = rec;
}

// ---- per-node self-loop attention terms = mean of stored ae over CSR range ----
__global__ void k_mean_self(const int* __restrict__ row_off, const uint4* __restrict__ csr,
                            float* __restrict__ a_e1s, float* __restrict__ a_e2s) {
    int n = blockIdx.x * blockDim.x + threadIdx.x;
    if (n >= NN) return;
    int beg = row_off[n], end = row_off[n + 1];
    float s0 = 0.f, s1 = 0.f, s2 = 0.f, s3 = 0.f, se = 0.f;
    for (int j = beg; j < end; ++j) {
        uint4 r = csr[j];
        float2 a01 = up2(r.y), a23 = up2(r.z), ap = up2(r.w);
        s0 += a01.x; s1 += a01.y; s2 += a23.x; s3 += a23.y; se += ap.x;
    }
    float inv = 1.0f / fmaxf((float)(end - beg), 1.0f);
    a_e1s[n * H1D + 0] = s0 * inv;
    a_e1s[n * H1D + 1] = s1 * inv;
    a_e1s[n * H1D + 2] = s2 * inv;
    a_e1s[n * H1D + 3] = s3 * inv;
    a_e2s[n] = se * inv;
}

// ---- xh1 = x @ W1 fused with attn dots; fp16 64B-aligned rows; thread per (n,h) ----
__global__ void k_xh1attn1(const float* __restrict__ x, const float* __restrict__ W1,
                           const float* __restrict__ as, const float* __restrict__ ad,
                           __half* __restrict__ xh1h, float* __restrict__ a_src1,
                           float* __restrict__ a_dst1) {
    __shared__ float sW[IND * H1D * FD];
    for (int i = threadIdx.x; i < IND * H1D * FD; i += blockDim.x) sW[i] = W1[i];
    __syncthreads();
    int idx = blockIdx.x * blockDim.x + threadIdx.x;
    if (idx >= NN * H1D) return;
    int n = idx >> 2, h = idx & 3;
    float xr[IND];
    const float4* xp = (const float4*)&x[(size_t)n * IND];
#pragma unroll
    for (int q = 0; q < IND / 4; ++q) {
        float4 v = xp[q];
        xr[4 * q] = v.x; xr[4 * q + 1] = v.y; xr[4 * q + 2] = v.z; xr[4 * q + 3] = v.w;
    }
    float ss = 0.f, sd = 0.f;
    float o[FD];
#pragma unroll
    for (int f = 0; f < FD; ++f) {
        float s = 0.f;
#pragma unroll
        for (int k = 0; k < IND; ++k) s += xr[k] * sW[k * (H1D * FD) + h * FD + f];
        o[f] = s;
        ss += s * as[h * FD + f];
        sd += s * ad[h * FD + f];
    }
    uint4* xo = (uint4*)&xh1h[((size_t)n * H1D + h) * FP];
    xo[0] = make_uint4(pack2(o[0], o[1]), pack2(o[2], o[3]), pack2(o[4], o[5]), pack2(o[6], o[7]));
    xo[1] = make_uint4(pack2(o[8], o[9]), pack2(o[10], o[11]), pack2(o[12], o[13]), pack2(o[14], o[15]));
    xo[2] = make_uint4(pack2(o[16], o[17]), pack2(o[18], o[19]), 0u, 0u);
    xo[3] = make_uint4(0u, 0u, 0u, 0u);
    a_src1[idx] = ss; a_dst1[idx] = sd;
}

#define FMA_PAYLOAD(ex, g0, g1, g2)                                     \
    {                                                                   \
        float2 f_;                                                      \
        f_ = up2(g0.x); acc[0] += (ex) * f_.x;  acc[1] += (ex) * f_.y;  \
        f_ = up2(g0.y); acc[2] += (ex) * f_.x;  acc[3] += (ex) * f_.y;  \
        f_ = up2(g0.z); acc[4] += (ex) * f_.x;  acc[5] += (ex) * f_.y;  \
        f_ = up2(g0.w); acc[6] += (ex) * f_.x;  acc[7] += (ex) * f_.y;  \
        f_ = up2(g1.x); acc[8] += (ex) * f_.x;  acc[9] += (ex) * f_.y;  \
        f_ = up2(g1.y); acc[10] += (ex) * f_.x; acc[11] += (ex) * f_.y; \
        f_ = up2(g1.z); acc[12] += (ex) * f_.x; acc[13] += (ex) * f_.y; \
        f_ = up2(g1.w); acc[14] += (ex) * f_.x; acc[15] += (ex) * f_.y; \
        f_ = up2(g2.x); acc[16] += (ex) * f_.x; acc[17] += (ex) * f_.y; \
        f_ = up2(g2.y); acc[18] += (ex) * f_.x; acc[19] += (ex) * f_.y; \
    }

// ---- conv1: 16 lanes/node (4 heads x 4 edge-splits), 2-stage modulo pipeline ----
__global__ __launch_bounds__(256) void k_conv1(
        const int* __restrict__ row_off, const uint4* __restrict__ csr,
        const float* __restrict__ a_src1, const float* __restrict__ a_dst1,
        const float* __restrict__ a_e1s, const __half* __restrict__ xh1h,
        const float* __restrict__ b1, float* __restrict__ h1) {
    int idx = blockIdx.x * 256 + threadIdx.x;     // [0, NN*16)
    int n = idx >> 4, low = idx & 15, h = low & 3, p = low >> 2;
    int beg = row_off[n], end = row_off[n + 1];
    float adst = a_dst1[n * H1D + h];
    float m, denom;
    float acc[FD];
#pragma unroll
    for (int f = 0; f < FD; ++f) acc[f] = 0.f;
    if (p == 0) {
        m = lrelu(a_src1[n * H1D + h] + adst + a_e1s[n * H1D + h]);
        denom = 1.0f;
        const uint4* xp = (const uint4*)&xh1h[((size_t)n * H1D + h) * FP];
        uint4 s0 = xp[0], s1 = xp[1];
        uint2 s2 = *(const uint2*)(xp + 2);
        FMA_PAYLOAD(1.0f, s0, s1, s2);
    } else {
        m = -1e30f; denom = 0.f;
    }
    int j = beg + p;
    uint4 rC, gC0, gC1; uint2 gC2; float avC;   // current: record+payload ready
    uint4 rN;                                    // next: record only
    if (j < end) {
        rC = csr[j];
        int s = (int)rC.x;
        avC = a_src1[s * H1D + h];
        const uint4* xp = (const uint4*)&xh1h[((size_t)s * H1D + h) * FP];
        gC0 = xp[0]; gC1 = xp[1]; gC2 = *(const uint2*)(xp + 2);
    }
    if (j + 4 < end) rN = csr[j + 4];
    while (j < end) {
        uint4 rNN;
        if (j + 8 < end) rNN = csr[j + 8];           // stage 2: record prefetch
        float avP; uint4 gP0, gP1; uint2 gP2;
        if (j + 4 < end) {                            // stage 1: payload for rN
            int s = (int)rN.x;
            avP = a_src1[s * H1D + h];
            const uint4* xp = (const uint4*)&xh1h[((size_t)s * H1D + h) * FP];
            gP0 = xp[0]; gP1 = xp[1]; gP2 = *(const uint2*)(xp + 2);
        }
        // stage 0: consume current
        unsigned wae = (h < 2) ? rC.y : rC.z;
        float2 aep = up2(wae);
        float ae = (h & 1) ? aep.y : aep.x;
        float l = lrelu(avC + adst + ae);
        if (l > m) {
            float sc = __expf(m - l);
            denom *= sc;
#pragma unroll
            for (int f = 0; f < FD; ++f) acc[f] *= sc;
            m = l;
        }
        float ex = __expf(l - m);
        denom += ex;
        FMA_PAYLOAD(ex, gC0, gC1, gC2);
        rC = rN; avC = avP; gC0 = gP0; gC1 = gP1; gC2 = gP2;
        rN = rNN;
        j += 4;
    }
    // merge 4 edge-split partials (p encoded in idx bits [3:2])
#pragma unroll
    for (int st = 4; st <= 8; st <<= 1) {
        float mo = __shfl_xor(m, st);
        float dno = __shfl_xor(denom, st);
        float M = fmaxf(m, mo);
        float ssf = __expf(m - M), sof = __expf(mo - M);
        denom = denom * ssf + dno * sof;
#pragma unroll
        for (int f = 0; f < FD; ++f) acc[f] = acc[f] * ssf + __shfl_xor(acc[f], st) * sof;
        m = M;
    }
    if (p) return;
    float inv = 1.0f / (denom + 1e-16f);
    float* ho = &h1[((size_t)n * H1D + h) * FD];
#pragma unroll
    for (int f = 0; f < FD; ++f) ho[f] = elu(acc[f] * inv + b1[h * FD + f]);
}

// ---- xh2 = h1 @ W2 fused with attn dots; fp16 64B-aligned row; thread per node ----
__global__ void k_xh2attn2(const float* __restrict__ h1, const float* __restrict__ W2,
                           const float* __restrict__ as, const float* __restrict__ ad,
                           __half* __restrict__ xh2h, float* __restrict__ a_src2,
                           float* __restrict__ a_dst2) {
    __shared__ float sW[H1D * FD * FD];
    for (int i = threadIdx.x; i < H1D * FD * FD; i += blockDim.x) sW[i] = W2[i];
    __syncthreads();
    int n = blockIdx.x * blockDim.x + threadIdx.x;
    if (n >= NN) return;
    float hr[H1D * FD];
    const float4* hp = (const float4*)&h1[(size_t)n * (H1D * FD)];
#pragma unroll
    for (int q = 0; q < (H1D * FD) / 4; ++q) {
        float4 v = hp[q];
        hr[4 * q] = v.x; hr[4 * q + 1] = v.y; hr[4 * q + 2] = v.z; hr[4 * q + 3] = v.w;
    }
    float ss = 0.f, sd = 0.f;
    float o[FD];
#pragma unroll
    for (int f = 0; f < FD; ++f) {
        float s = 0.f;
#pragma unroll
        for (int k = 0; k < H1D * FD; ++k) s += hr[k] * sW[k * FD + f];
        o[f] = s;
        ss += s * as[f];
        sd += s * ad[f];
    }
    uint4* xo = (uint4*)&xh2h[(size_t)n * FP];
    xo[0] = make_uint4(pack2(o[0], o[1]), pack2(o[2], o[3]), pack2(o[4], o[5]), pack2(o[6], o[7]));
    xo[1] = make_uint4(pack2(o[8], o[9]), pack2(o[10], o[11]), pack2(o[12], o[13]), pack2(o[14], o[15]));
    xo[2] = make_uint4(pack2(o[16], o[17]), pack2(o[18], o[19]), 0u, 0u);
    xo[3] = make_uint4(0u, 0u, 0u, 0u);
    a_src2[n] = ss; a_dst2[n] = sd;
}

// ---- conv2 (4 lanes/node edge-split, 2-stage pipeline) + elu + decoder MLP ----
__global__ __launch_bounds__(256) void k_conv2dec(
        const int* __restrict__ row_off, const uint4* __restrict__ csr,
        const float* __restrict__ a_src2, const float* __restrict__ a_dst2,
        const float* __restrict__ a_e2s, const __half* __restrict__ xh2h,
        const float* __restrict__ b2, const float* __restrict__ D1w,
        const float* __restrict__ D1b, const float* __restrict__ D2w,
        const float* __restrict__ D2b, float* __restrict__ out) {
    __shared__ float sD1w[FD * 10], sD1b[10], sD2w[10 * OUTD], sD2b[OUTD], sb2[FD];
    for (int i = threadIdx.x; i < FD * 10; i += blockDim.x) sD1w[i] = D1w[i];
    if (threadIdx.x < 10) sD1b[threadIdx.x] = D1b[threadIdx.x];
    if (threadIdx.x < 10 * OUTD) sD2w[threadIdx.x] = D2w[threadIdx.x];
    if (threadIdx.x < OUTD) sD2b[threadIdx.x] = D2b[threadIdx.x];
    if (threadIdx.x < FD) sb2[threadIdx.x] = b2[threadIdx.x];
    __syncthreads();
    int idx = blockIdx.x * 256 + threadIdx.x;     // [0, NN*4)
    if (idx >= NN * 4) return;
    int n = idx >> 2, p = idx & 3;
    int beg = row_off[n], end = row_off[n + 1];
    float adst = a_dst2[n];
    float m, denom;
    float acc[FD];
#pragma unroll
    for (int f = 0; f < FD; ++f) acc[f] = 0.f;
    if (p == 0) {
        m = lrelu(a_src2[n] + adst + a_e2s[n]);
        denom = 1.0f;
        const uint4* xp = (const uint4*)&xh2h[(size_t)n * FP];
        uint4 s0 = xp[0], s1 = xp[1];
        uint2 s2 = *(const uint2*)(xp + 2);
        FMA_PAYLOAD(1.0f, s0, s1, s2);
    } else {
        m = -1e30f; denom = 0.f;
    }
    int j = beg + p;
    uint4 rC, gC0, gC1; uint2 gC2; float avC;
    uint4 rN;
    if (j < end) {
        rC = csr[j];
        int s = (int)rC.x;
        avC = a_src2[s];
        const uint4* xp = (const uint4*)&xh2h[(size_t)s * FP];
        gC0 = xp[0]; gC1 = xp[1]; gC2 = *(const uint2*)(xp + 2);
    }
    if (j + 4 < end) rN = csr[j + 4];
    while (j < end) {
        uint4 rNN;
        if (j + 8 < end) rNN = csr[j + 8];
        float avP; uint4 gP0, gP1; uint2 gP2;
        if (j + 4 < end) {
            int s = (int)rN.x;
            avP = a_src2[s];
            const uint4* xp = (const uint4*)&xh2h[(size_t)s * FP];
            gP0 = xp[0]; gP1 = xp[1]; gP2 = *(const uint2*)(xp + 2);
        }
        float l = lrelu(avC + adst + up2(rC.w).x);
        if (l > m) {
            float sc = __expf(m - l);
            denom *= sc;
#pragma unroll
            for (int f = 0; f < FD; ++f) acc[f] *= sc;
            m = l;
        }
        float ex = __expf(l - m);
        denom += ex;
        FMA_PAYLOAD(ex, gC0, gC1, gC2);
        rC = rN; avC = avP; gC0 = gP0; gC1 = gP1; gC2 = gP2;
        rN = rNN;
        j += 4;
    }
#pragma unroll
    for (int st = 1; st <= 2; st <<= 1) {
        float mo = __shfl_xor(m, st);
        float dno = __shfl_xor(denom, st);
        float M = fmaxf(m, mo);
        float ssf = __expf(m - M), sof = __expf(mo - M);
        denom = denom * ssf + dno * sof;
#pragma unroll
        for (int f = 0; f < FD; ++f) acc[f] = acc[f] * ssf + __shfl_xor(acc[f], st) * sof;
        m = M;
    }
    if (p) return;
    float inv = 1.0f / (denom + 1e-16f);
    float h2[FD];
#pragma unroll
    for (int f = 0; f < FD; ++f) h2[f] = elu(acc[f] * inv + sb2[f]);
    float o[OUTD];
#pragma unroll
    for (int k = 0; k < OUTD; ++k) o[k] = sD2b[k];
    for (int j2 = 0; j2 < 10; ++j2) {
        float hid = sD1b[j2];
#pragma unroll
        for (int f = 0; f < FD; ++f) hid += h2[f] * sD1w[f * 10 + j2];
        hid = fmaxf(hid, 0.0f);
#pragma unroll
        for (int k = 0; k < OUTD; ++k) o[k] += hid * sD2w[j2 * OUTD + k];
    }
#pragma unroll
    for (int k = 0; k < OUTD; ++k) out[n * OUTD + k] = o[k];
}

extern "C" void kernel_launch(void* const* d_in, const int* in_sizes, int n_in,
                              void* d_out, int out_size, void* d_ws, size_t ws_size,
                              hipStream_t stream) {
    const float* x     = (const float*)d_in[0];
    const int*   ei    = (const int*)d_in[1];
    const float* eattr = (const float*)d_in[2];
    const float* W1    = (const float*)d_in[3];
    const float* as1   = (const float*)d_in[4];
    const float* ad1   = (const float*)d_in[5];
    const float* We1   = (const float*)d_in[6];
    const float* ae1   = (const float*)d_in[7];
    const float* b1    = (const float*)d_in[8];
    const float* W2    = (const float*)d_in[9];
    const float* as2   = (const float*)d_in[10];
    const float* ad2   = (const float*)d_in[11];
    const float* We2   = (const float*)d_in[12];
    const float* ae2   = (const float*)d_in[13];
    const float* b2    = (const float*)d_in[14];
    const float* D1w   = (const float*)d_in[15];
    const float* D1b   = (const float*)d_in[16];
    const float* D2w   = (const float*)d_in[17];
    const float* D2b   = (const float*)d_in[18];
    float* out = (float*)d_out;

    float* w = (float*)d_ws;
    size_t o = 0;
    // ---- zero-init region: only deg ----
    int*   deg = (int*)(w + o); o += NN;
    size_t zero_bytes = o * sizeof(float);
    // ---- rest (fully overwritten each call) ----
    int*   rank    = (int*)(w + o); o += EEg;
    int*   partial = (int*)(w + o); o += NN;
    int*   bsum    = (int*)(w + o); o += 256;
    int*   boff    = (int*)(w + o); o += 256;
    int*   row_off = (int*)(w + o); o += NN + 4;
    float* csr     = w + o; o += (size_t)EEg * 4;            // 16B records
    float* ve1     = w + o; o += 32;
    float* ve2     = w + o; o += 8;
    float* a_e1s   = w + o; o += (size_t)NN * H1D;
    float* a_e2s   = w + o; o += NN;
    float* a_src1  = w + o; o += (size_t)NN * H1D;
    float* a_dst1  = w + o; o += (size_t)NN * H1D;
    // align xh1h to 64B for line-aligned rows
    o = (o + 15) & ~(size_t)15;
    __half* xh1h   = (__half*)(w + o); o += (size_t)NN * H1D * FP / 2;
    float* h1      = w + o; o += (size_t)NN * H1D * FD;
    o = (o + 15) & ~(size_t)15;
    __half* xh2h   = (__half*)(w + o); o += (size_t)NN * FP / 2;
    float* a_src2  = w + o; o += NN;
    float* a_dst2  = w + o; o += NN;

    hipMemsetAsync(d_ws, 0, zero_bytes, stream);

    const int B = 256;
    auto cdiv = [](long a, long b) { return (int)((a + b - 1) / b); };
    const int NB = cdiv(NN, 256);

    k_deg<<<cdiv(EEg, B), B, 0, stream>>>(ei, deg, rank);
    k_ve<<<1, 64, 0, stream>>>(We1, ae1, We2, ae2, ve1, ve2);
    k_scanA<<<NB, 256, 0, stream>>>(deg, partial, bsum);
    k_scanB<<<1, 256, 0, stream>>>(bsum, boff, NB);
    k_scanC<<<NB, 256, 0, stream>>>(partial, boff, row_off);
    k_scatter<<<cdiv(EEg, B), B, 0, stream>>>(ei, eattr, ve1, ve2, row_off, rank,
                                              (uint4*)csr);
    k_mean_self<<<NB, 256, 0, stream>>>(row_off, (const uint4*)csr, a_e1s, a_e2s);
    k_xh1attn1<<<cdiv((long)NN * H1D, B), B, 0, stream>>>(x, W1, as1, ad1, xh1h, a_src1,
                                                          a_dst1);
    k_conv1<<<cdiv((long)NN * 16, 256), 256, 0, stream>>>(row_off, (const uint4*)csr,
                                                          a_src1, a_dst1, a_e1s, xh1h, b1,
                                                          h1);
    k_xh2attn2<<<NB, 256, 0, stream>>>(h1, W2, as2, ad2, xh2h, a_src2, a_dst2);
    k_conv2dec<<<cdiv((long)NN * 4, 256), 256, 0, stream>>>(row_off, (const uint4*)csr,
                                                            a_src2, a_dst2, a_e2s, xh2h,
                                                            b2, D1w, D1b, D2w, D2b, out);
}

// Round 16
// 266.351 us; speedup vs baseline: 1.1417x; 1.1417x over previous
//
#include <hip/hip_runtime.h>
#include <hip/hip_fp16.h>

// Problem constants (match reference)
constexpr int NN  = 50000;
constexpr int EEg = 1600000;          // edges before self-loops
constexpr int IND = 16;
constexpr int FD  = 20;
constexpr int H1D = 4;
constexpr int ED  = 7;
constexpr int OUTD = 3;
constexpr int FP  = 24;               // padded half-row (20 -> 24 halfs = 48B)

__device__ __forceinline__ float lrelu(float x) { return x >= 0.0f ? x : 0.2f * x; }
__device__ __forceinline__ float elu(float x)   { return x > 0.0f ? x : expm1f(x); }
__device__ __forceinline__ unsigned pack2(float a, float b) {
    __half2 h = __floats2half2_rn(a, b);
    return *(unsigned*)&h;
}
__device__ __forceinline__ float2 up2(unsigned w) {
    __half2 h = *(__half2*)&w;
    return __half22float2(h);
}

// ---- per-dst degree histogram; atomic return value = edge rank within dst ----
__global__ void k_deg(const int* __restrict__ ei, int* __restrict__ deg,
                      int* __restrict__ rank) {
    int e = blockIdx.x * blockDim.x + threadIdx.x;
    if (e >= EEg) return;
    rank[e] = atomicAdd(&deg[ei[EEg + e]], 1);
}

// ---- tiny: ve1[d*4+h] = sum_f We1[d,h*F+f]*att_e1[h,f]; ve2[d] likewise ----
__global__ void k_ve(const float* __restrict__ We1, const float* __restrict__ ae1,
                     const float* __restrict__ We2, const float* __restrict__ ae2,
                     float* __restrict__ ve1, float* __restrict__ ve2) {
    int t = threadIdx.x;
    if (t < ED * H1D) {
        int d = t >> 2, h = t & 3;
        float s = 0.0f;
        for (int f = 0; f < FD; ++f) s += We1[d * (H1D * FD) + h * FD + f] * ae1[h * FD + f];
        ve1[t] = s;
    } else if (t < ED * H1D + ED) {
        int d = t - ED * H1D;
        float s = 0.0f;
        for (int f = 0; f < FD; ++f) s += We2[d * FD + f] * ae2[f];
        ve2[d] = s;
    }
}

// ---- two-level exclusive scan for row_off ----
__global__ void k_scanA(const int* __restrict__ deg, int* __restrict__ partial,
                        int* __restrict__ bsum) {
    __shared__ int sd[256];
    int t = threadIdx.x, i = blockIdx.x * 256 + t;
    int v = (i < NN) ? deg[i] : 0;
    sd[t] = v;
    __syncthreads();
    for (int off = 1; off < 256; off <<= 1) {
        int u = (t >= off) ? sd[t - off] : 0;
        __syncthreads();
        sd[t] += u;
        __syncthreads();
    }
    if (i < NN) partial[i] = sd[t] - v;
    if (t == 255) bsum[blockIdx.x] = sd[255];
}
__global__ void k_scanB(const int* __restrict__ bsum, int* __restrict__ boff, int nb) {
    __shared__ int sd[256];
    int t = threadIdx.x;
    int v = (t < nb) ? bsum[t] : 0;
    sd[t] = v;
    __syncthreads();
    for (int off = 1; off < 256; off <<= 1) {
        int u = (t >= off) ? sd[t - off] : 0;
        __syncthreads();
        sd[t] += u;
        __syncthreads();
    }
    if (t < nb) boff[t] = sd[t] - v;
}
__global__ void k_scanC(const int* __restrict__ partial, const int* __restrict__ boff,
                        int* __restrict__ row_off) {
    int i = blockIdx.x * 256 + threadIdx.x;
    if (i < NN) row_off[i] = partial[i] + boff[blockIdx.x];
    if (i == 0) row_off[NN] = EEg;
}

// ---- scatter: ONE aligned 16B record per edge; eattr staged through LDS ----
// record: {x=src, y=half2(ae1_0,ae1_1), z=half2(ae1_2,ae1_3), w=half2(ae2,0)}
__global__ __launch_bounds__(256) void k_scatter(
        const int* __restrict__ ei, const float* __restrict__ eattr,
        const float* __restrict__ ve1, const float* __restrict__ ve2,
        const int* __restrict__ row_off, const int* __restrict__ rank,
        uint4* __restrict__ csr) {
    __shared__ float sv1[ED * H1D], sv2[ED];
    __shared__ float se[256 * ED];
    if (threadIdx.x < ED * H1D) sv1[threadIdx.x] = ve1[threadIdx.x];
    if (threadIdx.x < ED) sv2[threadIdx.x] = ve2[threadIdx.x];
    size_t gbase = (size_t)blockIdx.x * 256 * ED;
    for (int i = threadIdx.x; i < 256 * ED; i += 256) {
        size_t g = gbase + i;
        if (g < (size_t)EEg * ED) se[i] = eattr[g];
    }
    __syncthreads();
    int e = blockIdx.x * 256 + threadIdx.x;
    if (e >= EEg) return;
    int src = ei[e], dst = ei[EEg + e];
    const float* a = &se[threadIdx.x * ED];
    float v0 = 0.f, v1 = 0.f, v2 = 0.f, v3 = 0.f, w2 = 0.f;
#pragma unroll
    for (int d = 0; d < ED; ++d) {
        float ad = a[d];
        v0 += ad * sv1[d * H1D + 0];
        v1 += ad * sv1[d * H1D + 1];
        v2 += ad * sv1[d * H1D + 2];
        v3 += ad * sv1[d * H1D + 3];
        w2 += ad * sv2[d];
    }
    int slot = row_off[dst] + rank[e];
    uint4 rec;
    rec.x = (unsigned)src;
    rec.y = pack2(v0, v1);
    rec.z = pack2(v2, v3);
    rec.w = pack2(w2, 0.0f);
    csr[slot] = rec;
}

// ---- xh1 = x @ W1 fused with attn dots; fp16 padded rows out; thread per (n,h) ----
__global__ void k_xh1attn1(const float* __restrict__ x, const float* __restrict__ W1,
                           const float* __restrict__ as, const float* __restrict__ ad,
                           __half* __restrict__ xh1h, float* __restrict__ a_src1,
                           float* __restrict__ a_dst1) {
    __shared__ float sW[IND * H1D * FD];
    for (int i = threadIdx.x; i < IND * H1D * FD; i += blockDim.x) sW[i] = W1[i];
    __syncthreads();
    int idx = blockIdx.x * blockDim.x + threadIdx.x;
    if (idx >= NN * H1D) return;
    int n = idx >> 2, h = idx & 3;
    float xr[IND];
    const float4* xp = (const float4*)&x[(size_t)n * IND];
#pragma unroll
    for (int q = 0; q < IND / 4; ++q) {
        float4 v = xp[q];
        xr[4 * q] = v.x; xr[4 * q + 1] = v.y; xr[4 * q + 2] = v.z; xr[4 * q + 3] = v.w;
    }
    float ss = 0.f, sd = 0.f;
    float o[FD];
#pragma unroll
    for (int f = 0; f < FD; ++f) {
        float s = 0.f;
#pragma unroll
        for (int k = 0; k < IND; ++k) s += xr[k] * sW[k * (H1D * FD) + h * FD + f];
        o[f] = s;
        ss += s * as[h * FD + f];
        sd += s * ad[h * FD + f];
    }
    uint4* xo = (uint4*)&xh1h[((size_t)n * H1D + h) * FP];
    xo[0] = make_uint4(pack2(o[0], o[1]), pack2(o[2], o[3]), pack2(o[4], o[5]), pack2(o[6], o[7]));
    xo[1] = make_uint4(pack2(o[8], o[9]), pack2(o[10], o[11]), pack2(o[12], o[13]), pack2(o[14], o[15]));
    xo[2] = make_uint4(pack2(o[16], o[17]), pack2(o[18], o[19]), 0u, 0u);
    a_src1[idx] = ss; a_dst1[idx] = sd;
}

#define FMA_PAYLOAD(ex, g0, g1, g2)                                     \
    {                                                                   \
        float2 f_;                                                      \
        f_ = up2(g0.x); acc[0] += (ex) * f_.x;  acc[1] += (ex) * f_.y;  \
        f_ = up2(g0.y); acc[2] += (ex) * f_.x;  acc[3] += (ex) * f_.y;  \
        f_ = up2(g0.z); acc[4] += (ex) * f_.x;  acc[5] += (ex) * f_.y;  \
        f_ = up2(g0.w); acc[6] += (ex) * f_.x;  acc[7] += (ex) * f_.y;  \
        f_ = up2(g1.x); acc[8] += (ex) * f_.x;  acc[9] += (ex) * f_.y;  \
        f_ = up2(g1.y); acc[10] += (ex) * f_.x; acc[11] += (ex) * f_.y; \
        f_ = up2(g1.z); acc[12] += (ex) * f_.x; acc[13] += (ex) * f_.y; \
        f_ = up2(g1.w); acc[14] += (ex) * f_.x; acc[15] += (ex) * f_.y; \
        f_ = up2(g2.x); acc[16] += (ex) * f_.x; acc[17] += (ex) * f_.y; \
        f_ = up2(g2.y); acc[18] += (ex) * f_.x; acc[19] += (ex) * f_.y; \
    }

// ---- conv1: 16 lanes/node (4 heads x 4 edge-splits), 2-stage modulo pipeline;
//      self-loop (mean-attr) folded in AFTER the edge loop via sae reduction ----
__global__ __launch_bounds__(256) void k_conv1(
        const int* __restrict__ row_off, const uint4* __restrict__ csr,
        const float* __restrict__ a_src1, const float* __restrict__ a_dst1,
        const __half* __restrict__ xh1h, const float* __restrict__ b1,
        float* __restrict__ h1) {
    int idx = blockIdx.x * 256 + threadIdx.x;     // [0, NN*16)
    int n = idx >> 4, low = idx & 15, h = low & 3, p = low >> 2;
    int beg = row_off[n], end = row_off[n + 1];
    float adst = a_dst1[n * H1D + h];
    float m = -1e30f, denom = 0.f, sae = 0.f;
    float acc[FD];
#pragma unroll
    for (int f = 0; f < FD; ++f) acc[f] = 0.f;
    int j = beg + p;
    uint4 rC, gC0, gC1; uint2 gC2; float avC;   // current: record+payload ready
    uint4 rN;                                    // next: record only
    if (j < end) {
        rC = csr[j];
        int s = (int)rC.x;
        avC = a_src1[s * H1D + h];
        const uint4* xp = (const uint4*)&xh1h[((size_t)s * H1D + h) * FP];
        gC0 = xp[0]; gC1 = xp[1]; gC2 = *(const uint2*)(xp + 2);
    }
    if (j + 4 < end) rN = csr[j + 4];
    while (j < end) {
        uint4 rNN;
        if (j + 8 < end) rNN = csr[j + 8];           // stage 2: record prefetch
        float avP; uint4 gP0, gP1; uint2 gP2;
        if (j + 4 < end) {                            // stage 1: payload for rN
            int s = (int)rN.x;
            avP = a_src1[s * H1D + h];
            const uint4* xp = (const uint4*)&xh1h[((size_t)s * H1D + h) * FP];
            gP0 = xp[0]; gP1 = xp[1]; gP2 = *(const uint2*)(xp + 2);
        }
        // stage 0: consume current
        unsigned wae = (h < 2) ? rC.y : rC.z;
        float2 aep = up2(wae);
        float ae = (h & 1) ? aep.y : aep.x;
        sae += ae;
        float l = lrelu(avC + adst + ae);
        if (l > m) {
            float sc = __expf(m - l);
            denom *= sc;
#pragma unroll
            for (int f = 0; f < FD; ++f) acc[f] *= sc;
            m = l;
        }
        float ex = __expf(l - m);
        denom += ex;
        FMA_PAYLOAD(ex, gC0, gC1, gC2);
        rC = rN; avC = avP; gC0 = gP0; gC1 = gP1; gC2 = gP2;
        rN = rNN;
        j += 4;
    }
    // merge 4 edge-split partials (p encoded in idx bits [3:2]) + sae sum
#pragma unroll
    for (int st = 4; st <= 8; st <<= 1) {
        float mo = __shfl_xor(m, st);
        float dno = __shfl_xor(denom, st);
        sae += __shfl_xor(sae, st);
        float M = fmaxf(m, mo);
        float ssf = __expf(m - M), sof = __expf(mo - M);
        denom = denom * ssf + dno * sof;
#pragma unroll
        for (int f = 0; f < FD; ++f) acc[f] = acc[f] * ssf + __shfl_xor(acc[f], st) * sof;
        m = M;
    }
    if (p) return;
    // self-loop: a_edge = mean of ae over real edges (0 if deg==0)
    int dg = end - beg;
    float mean = sae / fmaxf((float)dg, 1.0f);
    float ls = lrelu(a_src1[n * H1D + h] + adst + mean);
    if (ls > m) {
        float sc = __expf(m - ls);
        denom *= sc;
#pragma unroll
        for (int f = 0; f < FD; ++f) acc[f] *= sc;
        m = ls;
    }
    float exs = __expf(ls - m);
    denom += exs;
    {
        const uint4* xp = (const uint4*)&xh1h[((size_t)n * H1D + h) * FP];
        uint4 s0 = xp[0], s1 = xp[1];
        uint2 s2 = *(const uint2*)(xp + 2);
        FMA_PAYLOAD(exs, s0, s1, s2);
    }
    float inv = 1.0f / (denom + 1e-16f);
    float* ho = &h1[((size_t)n * H1D + h) * FD];
#pragma unroll
    for (int f = 0; f < FD; ++f) ho[f] = elu(acc[f] * inv + b1[h * FD + f]);
}

// ---- xh2 = h1 @ W2 fused with attn dots; fp16 padded row out; thread per node ----
__global__ void k_xh2attn2(const float* __restrict__ h1, const float* __restrict__ W2,
                           const float* __restrict__ as, const float* __restrict__ ad,
                           __half* __restrict__ xh2h, float* __restrict__ a_src2,
                           float* __restrict__ a_dst2) {
    __shared__ float sW[H1D * FD * FD];
    for (int i = threadIdx.x; i < H1D * FD * FD; i += blockDim.x) sW[i] = W2[i];
    __syncthreads();
    int n = blockIdx.x * blockDim.x + threadIdx.x;
    if (n >= NN) return;
    float hr[H1D * FD];
    const float4* hp = (const float4*)&h1[(size_t)n * (H1D * FD)];
#pragma unroll
    for (int q = 0; q < (H1D * FD) / 4; ++q) {
        float4 v = hp[q];
        hr[4 * q] = v.x; hr[4 * q + 1] = v.y; hr[4 * q + 2] = v.z; hr[4 * q + 3] = v.w;
    }
    float ss = 0.f, sd = 0.f;
    float o[FD];
#pragma unroll
    for (int f = 0; f < FD; ++f) {
        float s = 0.f;
#pragma unroll
        for (int k = 0; k < H1D * FD; ++k) s += hr[k] * sW[k * FD + f];
        o[f] = s;
        ss += s * as[f];
        sd += s * ad[f];
    }
    uint4* xo = (uint4*)&xh2h[(size_t)n * FP];
    xo[0] = make_uint4(pack2(o[0], o[1]), pack2(o[2], o[3]), pack2(o[4], o[5]), pack2(o[6], o[7]));
    xo[1] = make_uint4(pack2(o[8], o[9]), pack2(o[10], o[11]), pack2(o[12], o[13]), pack2(o[14], o[15]));
    xo[2] = make_uint4(pack2(o[16], o[17]), pack2(o[18], o[19]), 0u, 0u);
    a_src2[n] = ss; a_dst2[n] = sd;
}

// ---- conv2 (4 lanes/node edge-split, 2-stage pipeline, fused self) + decoder ----
__global__ __launch_bounds__(256) void k_conv2dec(
        const int* __restrict__ row_off, const uint4* __restrict__ csr,
        const float* __restrict__ a_src2, const float* __restrict__ a_dst2,
        const __half* __restrict__ xh2h, const float* __restrict__ b2,
        const float* __restrict__ D1w, const float* __restrict__ D1b,
        const float* __restrict__ D2w, const float* __restrict__ D2b,
        float* __restrict__ out) {
    __shared__ float sD1w[FD * 10], sD1b[10], sD2w[10 * OUTD], sD2b[OUTD], sb2[FD];
    for (int i = threadIdx.x; i < FD * 10; i += blockDim.x) sD1w[i] = D1w[i];
    if (threadIdx.x < 10) sD1b[threadIdx.x] = D1b[threadIdx.x];
    if (threadIdx.x < 10 * OUTD) sD2w[threadIdx.x] = D2w[threadIdx.x];
    if (threadIdx.x < OUTD) sD2b[threadIdx.x] = D2b[threadIdx.x];
    if (threadIdx.x < FD) sb2[threadIdx.x] = b2[threadIdx.x];
    __syncthreads();
    int idx = blockIdx.x * 256 + threadIdx.x;     // [0, NN*4)
    if (idx >= NN * 4) return;
    int n = idx >> 2, p = idx & 3;
    int beg = row_off[n], end = row_off[n + 1];
    float adst = a_dst2[n];
    float m = -1e30f, denom = 0.f, sae = 0.f;
    float acc[FD];
#pragma unroll
    for (int f = 0; f < FD; ++f) acc[f] = 0.f;
    int j = beg + p;
    uint4 rC, gC0, gC1; uint2 gC2; float avC;
    uint4 rN;
    if (j < end) {
        rC = csr[j];
        int s = (int)rC.x;
        avC = a_src2[s];
        const uint4* xp = (const uint4*)&xh2h[(size_t)s * FP];
        gC0 = xp[0]; gC1 = xp[1]; gC2 = *(const uint2*)(xp + 2);
    }
    if (j + 4 < end) rN = csr[j + 4];
    while (j < end) {
        uint4 rNN;
        if (j + 8 < end) rNN = csr[j + 8];
        float avP; uint4 gP0, gP1; uint2 gP2;
        if (j + 4 < end) {
            int s = (int)rN.x;
            avP = a_src2[s];
            const uint4* xp = (const uint4*)&xh2h[(size_t)s * FP];
            gP0 = xp[0]; gP1 = xp[1]; gP2 = *(const uint2*)(xp + 2);
        }
        float ae = up2(rC.w).x;
        sae += ae;
        float l = lrelu(avC + adst + ae);
        if (l > m) {
            float sc = __expf(m - l);
            denom *= sc;
#pragma unroll
            for (int f = 0; f < FD; ++f) acc[f] *= sc;
            m = l;
        }
        float ex = __expf(l - m);
        denom += ex;
        FMA_PAYLOAD(ex, gC0, gC1, gC2);
        rC = rN; avC = avP; gC0 = gP0; gC1 = gP1; gC2 = gP2;
        rN = rNN;
        j += 4;
    }
#pragma unroll
    for (int st = 1; st <= 2; st <<= 1) {
        float mo = __shfl_xor(m, st);
        float dno = __shfl_xor(denom, st);
        sae += __shfl_xor(sae, st);
        float M = fmaxf(m, mo);
        float ssf = __expf(m - M), sof = __expf(mo - M);
        denom = denom * ssf + dno * sof;
#pragma unroll
        for (int f = 0; f < FD; ++f) acc[f] = acc[f] * ssf + __shfl_xor(acc[f], st) * sof;
        m = M;
    }
    if (p) return;
    int dg = end - beg;
    float mean = sae / fmaxf((float)dg, 1.0f);
    float ls = lrelu(a_src2[n] + adst + mean);
    if (ls > m) {
        float sc = __expf(m - ls);
        denom *= sc;
#pragma unroll
        for (int f = 0; f < FD; ++f) acc[f] *= sc;
        m = ls;
    }
    float exs = __expf(ls - m);
    denom += exs;
    {
        const uint4* xp = (const uint4*)&xh2h[(size_t)n * FP];
        uint4 s0 = xp[0], s1 = xp[1];
        uint2 s2 = *(const uint2*)(xp + 2);
        FMA_PAYLOAD(exs, s0, s1, s2);
    }
    float inv = 1.0f / (denom + 1e-16f);
    float h2[FD];
#pragma unroll
    for (int f = 0; f < FD; ++f) h2[f] = elu(acc[f] * inv + sb2[f]);
    float o[OUTD];
#pragma unroll
    for (int k = 0; k < OUTD; ++k) o[k] = sD2b[k];
    for (int j2 = 0; j2 < 10; ++j2) {
        float hid = sD1b[j2];
#pragma unroll
        for (int f = 0; f < FD; ++f) hid += h2[f] * sD1w[f * 10 + j2];
        hid = fmaxf(hid, 0.0f);
#pragma unroll
        for (int k = 0; k < OUTD; ++k) o[k] += hid * sD2w[j2 * OUTD + k];
    }
#pragma unroll
    for (int k = 0; k < OUTD; ++k) out[n * OUTD + k] = o[k];
}

extern "C" void kernel_launch(void* const* d_in, const int* in_sizes, int n_in,
                              void* d_out, int out_size, void* d_ws, size_t ws_size,
                              hipStream_t stream) {
    const float* x     = (const float*)d_in[0];
    const int*   ei    = (const int*)d_in[1];
    const float* eattr = (const float*)d_in[2];
    const float* W1    = (const float*)d_in[3];
    const float* as1   = (const float*)d_in[4];
    const float* ad1   = (const float*)d_in[5];
    const float* We1   = (const float*)d_in[6];
    const float* ae1   = (const float*)d_in[7];
    const float* b1    = (const float*)d_in[8];
    const float* W2    = (const float*)d_in[9];
    const float* as2   = (const float*)d_in[10];
    const float* ad2   = (const float*)d_in[11];
    const float* We2   = (const float*)d_in[12];
    const float* ae2   = (const float*)d_in[13];
    const float* b2    = (const float*)d_in[14];
    const float* D1w   = (const float*)d_in[15];
    const float* D1b   = (const float*)d_in[16];
    const float* D2w   = (const float*)d_in[17];
    const float* D2b   = (const float*)d_in[18];
    float* out = (float*)d_out;

    float* w = (float*)d_ws;
    size_t o = 0;
    // ---- zero-init region: only deg ----
    int*   deg = (int*)(w + o); o += NN;
    size_t zero_bytes = o * sizeof(float);
    // ---- rest (fully overwritten each call) ----
    int*   rank    = (int*)(w + o); o += EEg;
    int*   partial = (int*)(w + o); o += NN;
    int*   bsum    = (int*)(w + o); o += 256;
    int*   boff    = (int*)(w + o); o += 256;
    int*   row_off = (int*)(w + o); o += NN + 4;
    float* csr     = w + o; o += (size_t)EEg * 4;            // 16B records
    float* ve1     = w + o; o += 32;
    float* ve2     = w + o; o += 8;
    float* a_src1  = w + o; o += (size_t)NN * H1D;
    float* a_dst1  = w + o; o += (size_t)NN * H1D;
    __half* xh1h   = (__half*)(w + o); o += (size_t)NN * H1D * FP / 2;
    float* h1      = w + o; o += (size_t)NN * H1D * FD;
    __half* xh2h   = (__half*)(w + o); o += (size_t)NN * FP / 2;
    float* a_src2  = w + o; o += NN;
    float* a_dst2  = w + o; o += NN;

    hipMemsetAsync(d_ws, 0, zero_bytes, stream);

    const int B = 256;
    auto cdiv = [](long a, long b) { return (int)((a + b - 1) / b); };
    const int NB = cdiv(NN, 256);

    k_deg<<<cdiv(EEg, B), B, 0, stream>>>(ei, deg, rank);
    k_ve<<<1, 64, 0, stream>>>(We1, ae1, We2, ae2, ve1, ve2);
    k_scanA<<<NB, 256, 0, stream>>>(deg, partial, bsum);
    k_scanB<<<1, 256, 0, stream>>>(bsum, boff, NB);
    k_scanC<<<NB, 256, 0, stream>>>(partial, boff, row_off);
    k_scatter<<<cdiv(EEg, B), B, 0, stream>>>(ei, eattr, ve1, ve2, row_off, rank,
                                              (uint4*)csr);
    k_xh1attn1<<<cdiv((long)NN * H1D, B), B, 0, stream>>>(x, W1, as1, ad1, xh1h, a_src1,
                                                          a_dst1);
    k_conv1<<<cdiv((long)NN * 16, 256), 256, 0, stream>>>(row_off, (const uint4*)csr,
                                                          a_src1, a_dst1, xh1h, b1, h1);
    k_xh2attn2<<<NB, 256, 0, stream>>>(h1, W2, as2, ad2, xh2h, a_src2, a_dst2);
    k_conv2dec<<<cdiv((long)NN * 4, 256), 256, 0, stream>>>(row_off, (const uint4*)csr,
                                                            a_src2, a_dst2, xh2h, b2,
                                                            D1w, D1b, D2w, D2b, out);
}